// Round 18
// baseline (52.423 us; speedup 1.0000x reference)
//
#include <hip/hip_runtime.h>
#include <math.h>

#define LL 4096      // H*W
#define KK 256       // C
#define HH 64
#define WW 64
#define NHEAD 8
#define NPNT 16
#define HD 32        // C / NH
#define AST 264      // LDS A-tile row stride in u16 (528 B = bank-stride 4 mod 32)

typedef unsigned short u16;
typedef __attribute__((ext_vector_type(4))) float f32x4;
typedef __attribute__((ext_vector_type(2))) _Float16 h2;
typedef __attribute__((ext_vector_type(8))) _Float16 h8;

__device__ __forceinline__ u16 f2h(float x) {
    _Float16 h = (_Float16)x;
    return __builtin_bit_cast(unsigned short, h);
}
__device__ __forceinline__ float h2f(u16 h) {
    return (float)__builtin_bit_cast(_Float16, h);
}

// ---------------------------------------------------------------------------
// wprep_k: all weights -> f16. (unchanged from r17)
// Rows [0,768): wcat f16 (+ bcat bias f32). Rows [768,1024): pw -> f16.
// ---------------------------------------------------------------------------
__global__ __launch_bounds__(256) void wprep_k(
    const float* __restrict__ vw,  const float* __restrict__ vb,
    const float* __restrict__ adw, const float* __restrict__ adb,
    const float* __restrict__ atw, const float* __restrict__ atb,
    const float* __restrict__ sw,  const float* __restrict__ sb,
    const float* __restrict__ pw,
    u16* __restrict__ wh,
    float* __restrict__ bcat,
    u16* __restrict__ ph)
{
    const int row = blockIdx.x * 4 + (threadIdx.x >> 6);  // 0..1023
    const int c   = threadIdx.x & 63;

    if (row < 768) {
        const float* src = nullptr;
        float bv = 0.f;
        const int o = row;
        if (o < 256)      { src = vw  + (size_t)o * KK;        bv = vb[o]; }
        else if (o < 512) { src = adw + (size_t)(o-256) * KK;  bv = adb[o-256]; }
        else if (o < 640) { src = atw + (size_t)(o-512) * KK;  bv = atb[o-512]; }
        else if (o < 656) { src = sw  + (size_t)(o-640) * KK;  bv = sb[o-640]; }
        if (c == 0) bcat[o] = bv;

        float4 v = {0.f, 0.f, 0.f, 0.f};
        if (src) v = *(const float4*)(src + c * 4);
        ushort4 hv;
        hv.x = f2h(v.x); hv.y = f2h(v.y); hv.z = f2h(v.z); hv.w = f2h(v.w);
        *(ushort4*)(wh + (size_t)row * KK + c * 4) = hv;
    } else {
        const int o = row - 768;
        float4 v = *(const float4*)(pw + (size_t)o * KK + c * 4);
        ushort4 hv;
        hv.x = f2h(v.x); hv.y = f2h(v.y); hv.z = f2h(v.z); hv.w = f2h(v.w);
        *(ushort4*)(ph + (size_t)o * KK + c * 4) = hv;
    }
}

// ---------------------------------------------------------------------------
// projf_k: fused feat-transpose + projection GEMM, all-f16.
// BM=32 px, 256 threads (4 waves), grid = 3 gy x 256 mb = 768 blocks
// = exactly 3 blocks/CU (balanced; was 384 blocks -> 1.5/CU tail-bound).
// LDS 16.9 KB. Wave n-tile = 64 cols.
//   gy==0: value cols 0..255  -> mem2 (f16)
//   gy==1: offset cols 256..511 -> rawp (f16)
//   gy==2: waves 0-1 att 512..639, wave 2 size 640..703 (16 real),
//          wave 3 cols 704..767 all-pad -> early return
// ---------------------------------------------------------------------------
__global__ __launch_bounds__(256) void projf_k(
    const float* __restrict__ feat,
    const u16* __restrict__ Wh,
    const float* __restrict__ bias,
    u16* __restrict__ mem2, u16* __restrict__ rawp)
{
    __shared__ u16 Ah[32][AST];

    const int bx = blockIdx.x;
    const int gy = bx % 3;
    const int mb = bx / 3;            // 0..255
    const int m0g = mb * 32;          // global pixel base (never crosses b)
    const int b   = m0g >> 12;
    const int l0  = m0g & (LL - 1);
    const int tid = threadIdx.x;
    const bool VAL = (gy == 0);

    // ---- stage A tile: 32 px x 256 k, f32 -> f16 ----
    {
        const int px = tid & 31;
        const int kb = (tid >> 5) * 32;   // 8 k-groups of 32
        const float* fp = feat + ((size_t)(b * KK + kb)) * LL + l0 + px;
        #pragma unroll
        for (int cch = 0; cch < 4; ++cch) {
            float xs[8];
            #pragma unroll
            for (int j = 0; j < 8; ++j)
                xs[j] = fp[(size_t)(cch * 8 + j) * LL];
            ushort4 a, c;
            a.x = f2h(xs[0]); a.y = f2h(xs[1]); a.z = f2h(xs[2]); a.w = f2h(xs[3]);
            c.x = f2h(xs[4]); c.y = f2h(xs[5]); c.z = f2h(xs[6]); c.w = f2h(xs[7]);
            *(ushort4*)&Ah[px][kb + cch * 8]     = a;
            *(ushort4*)&Ah[px][kb + cch * 8 + 4] = c;
        }
    }
    __syncthreads();

    const int lam  = tid & 63;
    const int wave = tid >> 6;        // 0..3

    if (gy == 2 && wave == 3) return;             // all-pad columns

    const int row  = lam & 15;
    const int kq   = (lam >> 4) * 8;
    const int n0   = gy * 256 + wave * 64;

    f32x4 acc[2][4];
    #pragma unroll
    for (int i = 0; i < 2; ++i)
        #pragma unroll
        for (int j = 0; j < 4; ++j)
            acc[i][j] = (f32x4){0.f, 0.f, 0.f, 0.f};

    #pragma unroll
    for (int s = 0; s < 8; ++s) {
        const int k0 = s * 32;
        h8 ah[2], bh[4];
        #pragma unroll
        for (int mf = 0; mf < 2; ++mf)
            ah[mf] = *(const h8*)(const void*)&Ah[mf * 16 + row][k0 + kq];
        #pragma unroll
        for (int nf = 0; nf < 4; ++nf)
            bh[nf] = *(const h8*)(const void*)(Wh + ((size_t)(n0 + nf * 16 + row)) * KK + k0 + kq);
        #pragma unroll
        for (int mf = 0; mf < 2; ++mf)
            #pragma unroll
            for (int nf = 0; nf < 4; ++nf)
                acc[mf][nf] = __builtin_amdgcn_mfma_f32_16x16x32_f16(ah[mf], bh[nf], acc[mf][nf], 0, 0, 0);
    }

    // ---- epilogue ----
    float bj[4];
    #pragma unroll
    for (int nf = 0; nf < 4; ++nf) bj[nf] = bias[n0 + nf * 16 + row];

    #pragma unroll
    for (int mf = 0; mf < 2; ++mf)
        #pragma unroll
        for (int r = 0; r < 4; ++r) {
            const int m  = m0g + mf * 16 + 4 * (lam >> 4) + r;
            const int bb = m >> 12;
            const int ll = m & (LL - 1);
            #pragma unroll
            for (int nf = 0; nf < 4; ++nf) {
                const int o = n0 + nf * 16 + row;
                const float v = acc[mf][nf][r] + bj[nf];
                if (VAL) {
                    mem2[(((size_t)(bb * NHEAD + (o >> 5)) * LL + ll) * HD) + (o & 31)] = f2h(v);
                } else if (o < 640) {
                    rawp[((size_t)(bb * LL + ll)) * 400 + (o - 240)] = f2h(v);   // offset/att
                } else if (o < 656) {
                    rawp[((size_t)(bb * LL + ll)) * 400 + (o - 640)] = f2h(v);   // size
                }
            }
        }
}

// ---------------------------------------------------------------------------
// Out projection + BN: 64x64 wave tile, grid (4,128), 1 f16-MFMA. (r15 config)
// ---------------------------------------------------------------------------
__global__ __launch_bounds__(64) void mgemm1_k(
    const u16* __restrict__ Ah,
    const u16* __restrict__ Bh,
    const float* __restrict__ gamma, const float* __restrict__ beta,
    float* __restrict__ out)
{
    const int lam = threadIdx.x;
    const int m0 = blockIdx.x * 64;
    const int n0 = blockIdx.y * 64;
    const int row = lam & 15;
    const int kq  = (lam >> 4) * 8;

    f32x4 acc[4][4];
    #pragma unroll
    for (int i = 0; i < 4; ++i)
        #pragma unroll
        for (int j = 0; j < 4; ++j)
            acc[i][j] = (f32x4){0.f, 0.f, 0.f, 0.f};

    #pragma unroll
    for (int s = 0; s < 8; ++s) {
        const int k0 = s * 32;
        h8 ah[4], bh[4];
        #pragma unroll
        for (int mf = 0; mf < 4; ++mf)
            ah[mf] = *(const h8*)(const void*)(Ah + ((size_t)(m0 + mf * 16 + row)) * KK + k0 + kq);
        #pragma unroll
        for (int nf = 0; nf < 4; ++nf)
            bh[nf] = *(const h8*)(const void*)(Bh + ((size_t)(n0 + nf * 16 + row)) * KK + k0 + kq);
        #pragma unroll
        for (int mf = 0; mf < 4; ++mf)
            #pragma unroll
            for (int nf = 0; nf < 4; ++nf)
                acc[mf][nf] = __builtin_amdgcn_mfma_f32_16x16x32_f16(ah[mf], bh[nf], acc[mf][nf], 0, 0, 0);
    }

    #pragma unroll
    for (int mf = 0; mf < 4; ++mf)
        #pragma unroll
        for (int r = 0; r < 4; ++r) {
            const int o = m0 + mf * 16 + 4 * (lam >> 4) + r;   // channel
            const float sc = gamma[o] / sqrtf(1.f + 1e-5f);
            const float be = beta[o];
            #pragma unroll
            for (int nf = 0; nf < 4; ++nf) {
                const int lg = n0 + nf * 16 + row;             // global pixel
                const int b  = lg >> 12;
                const int ll = lg & (LL - 1);
                out[((size_t)(b * KK + o)) * LL + ll] = acc[mf][nf][r] * sc + be;
            }
        }
}

// ---------------------------------------------------------------------------
// sample5_k: row-pair b128 gather sampler, f16 dot2 inner loop.
// rawp now f16 (halved phase-1 traffic); logic unchanged from r15.
// ---------------------------------------------------------------------------
__global__ __launch_bounds__(256) void sample5_k(
    const u16* __restrict__ mem2,
    const u16* __restrict__ rawp,
    u16* __restrict__ preH)
{
    __shared__ float srec[32][17][4];   // {off-as-int, wx, wy, wp}

    const int tid = threadIdx.x;

    #pragma unroll
    for (int q = 0; q < 2; ++q) {
        const int t  = q * 256 + tid;
        const int gi = t >> 4;
        const int p  = t & 15;
        const int g  = blockIdx.x * 32 + gi;
        const int l  = g & (LL - 1);
        const int h  = (g >> 12) & (NHEAD - 1);
        const int b  = g >> 15;
        const u16* rb = rawp + ((size_t)(b * LL + l)) * 400;

        float logit = h2f(rb[272 + h * NPNT + p]);
        float m = logit;
        m = fmaxf(m, __shfl_xor(m, 1));
        m = fmaxf(m, __shfl_xor(m, 2));
        m = fmaxf(m, __shfl_xor(m, 4));
        m = fmaxf(m, __shfl_xor(m, 8));
        float e = __expf(logit - m);
        float s = e;
        s += __shfl_xor(s, 1);
        s += __shfl_xor(s, 2);
        s += __shfl_xor(s, 4);
        s += __shfl_xor(s, 8);
        const float wp = e / s;

        float s0 = h2f(rb[h * 2 + 0]);
        float s1 = h2f(rb[h * 2 + 1]);
        s0 = fminf(fmaxf(1.f / (1.f + __expf(-s0)), 0.25f), 0.75f);
        s1 = fminf(fmaxf(1.f / (1.f + __expf(-s1)), 0.25f), 0.75f);

        const unsigned oo = *(const unsigned*)(const void*)(rb + 16 + (h * NPNT + p) * 2);
        const float o0 = 1.f / (1.f + __expf(-h2f((u16)(oo & 0xffffu))));
        const float o1 = 1.f / (1.f + __expf(-h2f((u16)(oo >> 16))));

        const int xl = l & (WW - 1);
        const int yl = l >> 6;
        const float cx = ((float)xl + 0.5f) / ((float)WW + 1e-6f);
        const float cy = ((float)yl + 0.5f) / ((float)HH + 1e-6f);

        float gx = fminf(fmaxf(cx - 0.5f * s0 + o0 * s0, 0.f), 1.f);
        float gy = fminf(fmaxf(cy - 0.5f * s1 + o1 * s1, 0.f), 1.f);
        const float ix = gx * (float)(WW - 1);
        const float iy = gy * (float)(HH - 1);
        const int x0 = min(max((int)floorf(ix), 0), WW - 2);
        const int y0 = min(max((int)floorf(iy), 0), HH - 2);
        const float wx = ix - (float)x0;
        const float wy = iy - (float)y0;

        srec[gi][p][0] = __int_as_float((y0 * WW + x0) * HD);
        srec[gi][p][1] = wx;
        srec[gi][p][2] = wy;
        srec[gi][p][3] = wp;
    }
    __syncthreads();

    const int gi = tid >> 3;
    const int j  = tid & 7;
    const int g  = blockIdx.x * 32 + gi;
    const int l  = g & (LL - 1);
    const int h  = (g >> 12) & (NHEAD - 1);
    const int b  = g >> 15;
    const u16* mb = mem2 + (size_t)(b * NHEAD + h) * LL * HD + j * 8;
    const bool hiSide = (j >= 4);

    float acc[8] = {};
    #pragma unroll
    for (int p = 0; p < NPNT; ++p) {
        const float4 rec = *(const float4*)&srec[gi][p][0];
        const int off   = __float_as_int(rec.x);
        const float fx  = hiSide ? rec.y : (1.f - rec.y);
        const float wf  = rec.w * fx;
        const h2 wp2 = __builtin_bit_cast(h2,
            __builtin_amdgcn_cvt_pkrtz(wf * (1.f - rec.z), wf * rec.z));
        const u16* p0 = mb + off;
        const uint4 V0 = *(const uint4*)(const void*)p0;               // row y0
        const uint4 V1 = *(const uint4*)(const void*)(p0 + WW * HD);   // row y0+1
        const unsigned v0w[4] = {V0.x, V0.y, V0.z, V0.w};
        const unsigned v1w[4] = {V1.x, V1.y, V1.z, V1.w};
        #pragma unroll
        for (int wd = 0; wd < 4; ++wd) {
            const unsigned plo = __builtin_amdgcn_perm(v1w[wd], v0w[wd], 0x05040100u);
            const unsigned phi = __builtin_amdgcn_perm(v1w[wd], v0w[wd], 0x07060302u);
            acc[2*wd]   = __builtin_amdgcn_fdot2(__builtin_bit_cast(h2, plo), wp2, acc[2*wd],   false);
            acc[2*wd+1] = __builtin_amdgcn_fdot2(__builtin_bit_cast(h2, phi), wp2, acc[2*wd+1], false);
        }
    }

    #pragma unroll
    for (int e = 0; e < 8; ++e)
        acc[e] += __shfl_xor(acc[e], 4);   // combine x0-side + x1-side

    if (j < 4) {
        ushort4 ha, hb;
        ha.x = f2h(acc[0]); ha.y = f2h(acc[1]); ha.z = f2h(acc[2]); ha.w = f2h(acc[3]);
        hb.x = f2h(acc[4]); hb.y = f2h(acc[5]); hb.z = f2h(acc[6]); hb.w = f2h(acc[7]);
        u16* dst = preH + ((size_t)(b * LL + l)) * KK + h * HD + j * 8;
        *(ushort4*)dst       = ha;
        *(ushort4*)(dst + 4) = hb;
    }
}

extern "C" void kernel_launch(void* const* d_in, const int* in_sizes, int n_in,
                              void* d_out, int out_size, void* d_ws, size_t ws_size,
                              hipStream_t stream) {
    const float* feat  = (const float*)d_in[0];
    const float* vw    = (const float*)d_in[1];
    const float* vb    = (const float*)d_in[2];
    const float* sw    = (const float*)d_in[3];
    const float* sb    = (const float*)d_in[4];
    const float* adw   = (const float*)d_in[5];
    const float* adb   = (const float*)d_in[6];
    const float* atw   = (const float*)d_in[7];
    const float* atb   = (const float*)d_in[8];
    const float* pw    = (const float*)d_in[9];
    const float* gamma = (const float*)d_in[10];
    const float* beta  = (const float*)d_in[11];
    float* out = (float*)d_out;
    char* ws = (char*)d_ws;

    // workspace layout (bytes)
    u16* mem2   = (u16*)(ws + 0);          // 4 MB (f16)
    u16* rawp   = (u16*)(ws + 4194304);    // 6.55 MB (f16, B*L*400)
    u16* preH   = (u16*)(ws + 10747904);   // 4 MB (f16)
    u16* wch    = (u16*)(ws + 14942208);   // 384 KB (768 rows, f16)
    float* bcat = (float*)(ws + 15335424); // 3 KB
    u16* pwh    = (u16*)(ws + 15339520);   // 128 KB (f16)

    // weights -> f16
    wprep_k<<<dim3(256), dim3(256), 0, stream>>>(vw, vb, adw, adb, atw, atb,
                                                 sw, sb, pw, wch, bcat, pwh);
    // fused feat-stage + all projections (BM=32, 768 blocks = 3/CU balanced)
    projf_k<<<dim3(768), dim3(256), 0, stream>>>(feat, wch, bcat, mem2, rawp);
    // sampling -> preH f16 (f16 dot2 gathers, f16 rawp)
    sample5_k<<<dim3(2048), dim3(256), 0, stream>>>(mem2, rawp, preH);
    // out projection + BN (f16 MFMA)
    mgemm1_k<<<dim3(4, 128), dim3(64), 0, stream>>>(pwh, preH, gamma, beta, out);
}

// Round 19
// 49.595 us; speedup vs baseline: 1.0570x; 1.0570x over previous
//
#include <hip/hip_runtime.h>
#include <math.h>

#define LL 4096      // H*W
#define KK 256       // C
#define HH 64
#define WW 64
#define NHEAD 8
#define NPNT 16
#define HD 32        // C / NH
#define AST 264      // LDS A-tile row stride in u16 (528 B = bank-stride 4 mod 32)

typedef unsigned short u16;
typedef __attribute__((ext_vector_type(4))) float f32x4;
typedef __attribute__((ext_vector_type(2))) _Float16 h2;
typedef __attribute__((ext_vector_type(8))) _Float16 h8;

__device__ __forceinline__ u16 f2h(float x) {
    _Float16 h = (_Float16)x;
    return __builtin_bit_cast(unsigned short, h);
}
__device__ __forceinline__ float h2f(u16 h) {
    return (float)__builtin_bit_cast(_Float16, h);
}

// ---------------------------------------------------------------------------
// wprep_k: all weights -> f16.
// Rows [0,768): wcat f16 (+ bcat bias f32). Rows [768,1024): pw -> f16.
// ---------------------------------------------------------------------------
__global__ __launch_bounds__(256) void wprep_k(
    const float* __restrict__ vw,  const float* __restrict__ vb,
    const float* __restrict__ adw, const float* __restrict__ adb,
    const float* __restrict__ atw, const float* __restrict__ atb,
    const float* __restrict__ sw,  const float* __restrict__ sb,
    const float* __restrict__ pw,
    u16* __restrict__ wh,
    float* __restrict__ bcat,
    u16* __restrict__ ph)
{
    const int row = blockIdx.x * 4 + (threadIdx.x >> 6);  // 0..1023
    const int c   = threadIdx.x & 63;

    if (row < 768) {
        const float* src = nullptr;
        float bv = 0.f;
        const int o = row;
        if (o < 256)      { src = vw  + (size_t)o * KK;        bv = vb[o]; }
        else if (o < 512) { src = adw + (size_t)(o-256) * KK;  bv = adb[o-256]; }
        else if (o < 640) { src = atw + (size_t)(o-512) * KK;  bv = atb[o-512]; }
        else if (o < 656) { src = sw  + (size_t)(o-640) * KK;  bv = sb[o-640]; }
        if (c == 0) bcat[o] = bv;

        float4 v = {0.f, 0.f, 0.f, 0.f};
        if (src) v = *(const float4*)(src + c * 4);
        ushort4 hv;
        hv.x = f2h(v.x); hv.y = f2h(v.y); hv.z = f2h(v.z); hv.w = f2h(v.w);
        *(ushort4*)(wh + (size_t)row * KK + c * 4) = hv;
    } else {
        const int o = row - 768;
        float4 v = *(const float4*)(pw + (size_t)o * KK + c * 4);
        ushort4 hv;
        hv.x = f2h(v.x); hv.y = f2h(v.y); hv.z = f2h(v.z); hv.w = f2h(v.w);
        *(ushort4*)(ph + (size_t)o * KK + c * 4) = hv;
    }
}

// ---------------------------------------------------------------------------
// projf_k: fused feat-transpose + projection GEMM, all-f16. (r17 geometry)
// BM=64 px, 512 threads (8 waves), grid = 3 gy x 128 mb = 384 blocks.
// Big BM amortizes the B-panel (each weight panel read by 128 not 256
// blocks) -- measured better than BM=32 balance (r18 post-mortem).
//   gy==0: value cols 0..255  -> mem2 (f16)
//   gy==1: offset cols 256..511 -> rawp (f16)
//   gy==2: waves 0-3 att 512..639, wave 4 size 640..671, waves 5-7 return
// ---------------------------------------------------------------------------
__global__ __launch_bounds__(512, 4) void projf_k(
    const float* __restrict__ feat,
    const u16* __restrict__ Wh,
    const float* __restrict__ bias,
    u16* __restrict__ mem2, u16* __restrict__ rawp)
{
    __shared__ u16 Ah[64][AST];

    const int bx = blockIdx.x;
    const int gy = bx % 3;
    const int mb = bx / 3;            // 0..127
    const int m0g = mb * 64;          // global pixel base (never crosses b)
    const int b   = m0g >> 12;
    const int l0  = m0g & (LL - 1);
    const int tid = threadIdx.x;
    const bool VAL = (gy == 0);

    // ---- stage A tile: 64 px x 256 k, f32 -> f16 ----
    {
        const int px = tid & 63;
        const int kb = (tid >> 6) * 32;   // 8 k-groups of 32
        const float* fp = feat + ((size_t)(b * KK + kb)) * LL + l0 + px;
        #pragma unroll
        for (int cch = 0; cch < 4; ++cch) {
            float xs[8];
            #pragma unroll
            for (int j = 0; j < 8; ++j)
                xs[j] = fp[(size_t)(cch * 8 + j) * LL];
            ushort4 a, c;
            a.x = f2h(xs[0]); a.y = f2h(xs[1]); a.z = f2h(xs[2]); a.w = f2h(xs[3]);
            c.x = f2h(xs[4]); c.y = f2h(xs[5]); c.z = f2h(xs[6]); c.w = f2h(xs[7]);
            *(ushort4*)&Ah[px][kb + cch * 8]     = a;
            *(ushort4*)&Ah[px][kb + cch * 8 + 4] = c;
        }
    }
    __syncthreads();

    const int lam  = tid & 63;
    const int wave = tid >> 6;        // 0..7

    if (gy == 2 && wave >= 5) return;             // zero-pad columns

    const int row  = lam & 15;
    const int kq   = (lam >> 4) * 8;
    const int n0   = gy * 256 + wave * 32;

    f32x4 acc[4][2];
    #pragma unroll
    for (int i = 0; i < 4; ++i)
        #pragma unroll
        for (int j = 0; j < 2; ++j)
            acc[i][j] = (f32x4){0.f, 0.f, 0.f, 0.f};

    #pragma unroll
    for (int s = 0; s < 8; ++s) {
        const int k0 = s * 32;
        h8 ah[4], bh[2];
        #pragma unroll
        for (int mf = 0; mf < 4; ++mf)
            ah[mf] = *(const h8*)(const void*)&Ah[mf * 16 + row][k0 + kq];
        #pragma unroll
        for (int nf = 0; nf < 2; ++nf)
            bh[nf] = *(const h8*)(const void*)(Wh + ((size_t)(n0 + nf * 16 + row)) * KK + k0 + kq);
        #pragma unroll
        for (int mf = 0; mf < 4; ++mf)
            #pragma unroll
            for (int nf = 0; nf < 2; ++nf)
                acc[mf][nf] = __builtin_amdgcn_mfma_f32_16x16x32_f16(ah[mf], bh[nf], acc[mf][nf], 0, 0, 0);
    }

    // ---- epilogue ----
    float bj[2];
    #pragma unroll
    for (int nf = 0; nf < 2; ++nf) bj[nf] = bias[n0 + nf * 16 + row];

    #pragma unroll
    for (int mf = 0; mf < 4; ++mf)
        #pragma unroll
        for (int r = 0; r < 4; ++r) {
            const int m  = m0g + mf * 16 + 4 * (lam >> 4) + r;
            const int bb = m >> 12;
            const int ll = m & (LL - 1);
            #pragma unroll
            for (int nf = 0; nf < 2; ++nf) {
                const int o = n0 + nf * 16 + row;
                const float v = acc[mf][nf][r] + bj[nf];
                if (VAL) {
                    mem2[(((size_t)(bb * NHEAD + (o >> 5)) * LL + ll) * HD) + (o & 31)] = f2h(v);
                } else if (o < 640) {
                    rawp[((size_t)(bb * LL + ll)) * 400 + (o - 240)] = f2h(v);   // offset/att
                } else if (o < 656) {
                    rawp[((size_t)(bb * LL + ll)) * 400 + (o - 640)] = f2h(v);   // size
                }
            }
        }
}

// ---------------------------------------------------------------------------
// Out projection + BN: 64x64 wave tile, grid (4,128), 1 f16-MFMA.
// ---------------------------------------------------------------------------
__global__ __launch_bounds__(64) void mgemm1_k(
    const u16* __restrict__ Ah,
    const u16* __restrict__ Bh,
    const float* __restrict__ gamma, const float* __restrict__ beta,
    float* __restrict__ out)
{
    const int lam = threadIdx.x;
    const int m0 = blockIdx.x * 64;
    const int n0 = blockIdx.y * 64;
    const int row = lam & 15;
    const int kq  = (lam >> 4) * 8;

    f32x4 acc[4][4];
    #pragma unroll
    for (int i = 0; i < 4; ++i)
        #pragma unroll
        for (int j = 0; j < 4; ++j)
            acc[i][j] = (f32x4){0.f, 0.f, 0.f, 0.f};

    #pragma unroll
    for (int s = 0; s < 8; ++s) {
        const int k0 = s * 32;
        h8 ah[4], bh[4];
        #pragma unroll
        for (int mf = 0; mf < 4; ++mf)
            ah[mf] = *(const h8*)(const void*)(Ah + ((size_t)(m0 + mf * 16 + row)) * KK + k0 + kq);
        #pragma unroll
        for (int nf = 0; nf < 4; ++nf)
            bh[nf] = *(const h8*)(const void*)(Bh + ((size_t)(n0 + nf * 16 + row)) * KK + k0 + kq);
        #pragma unroll
        for (int mf = 0; mf < 4; ++mf)
            #pragma unroll
            for (int nf = 0; nf < 4; ++nf)
                acc[mf][nf] = __builtin_amdgcn_mfma_f32_16x16x32_f16(ah[mf], bh[nf], acc[mf][nf], 0, 0, 0);
    }

    #pragma unroll
    for (int mf = 0; mf < 4; ++mf)
        #pragma unroll
        for (int r = 0; r < 4; ++r) {
            const int o = m0 + mf * 16 + 4 * (lam >> 4) + r;   // channel
            const float sc = gamma[o] / sqrtf(1.f + 1e-5f);
            const float be = beta[o];
            #pragma unroll
            for (int nf = 0; nf < 4; ++nf) {
                const int lg = n0 + nf * 16 + row;             // global pixel
                const int b  = lg >> 12;
                const int ll = lg & (LL - 1);
                out[((size_t)(b * KK + o)) * LL + ll] = acc[mf][nf][r] * sc + be;
            }
        }
}

// ---------------------------------------------------------------------------
// sample5_k: row-pair b128 gather sampler, f16 dot2 inner loop, f16 rawp.
// ---------------------------------------------------------------------------
__global__ __launch_bounds__(256) void sample5_k(
    const u16* __restrict__ mem2,
    const u16* __restrict__ rawp,
    u16* __restrict__ preH)
{
    __shared__ float srec[32][17][4];   // {off-as-int, wx, wy, wp}

    const int tid = threadIdx.x;

    #pragma unroll
    for (int q = 0; q < 2; ++q) {
        const int t  = q * 256 + tid;
        const int gi = t >> 4;
        const int p  = t & 15;
        const int g  = blockIdx.x * 32 + gi;
        const int l  = g & (LL - 1);
        const int h  = (g >> 12) & (NHEAD - 1);
        const int b  = g >> 15;
        const u16* rb = rawp + ((size_t)(b * LL + l)) * 400;

        float logit = h2f(rb[272 + h * NPNT + p]);
        float m = logit;
        m = fmaxf(m, __shfl_xor(m, 1));
        m = fmaxf(m, __shfl_xor(m, 2));
        m = fmaxf(m, __shfl_xor(m, 4));
        m = fmaxf(m, __shfl_xor(m, 8));
        float e = __expf(logit - m);
        float s = e;
        s += __shfl_xor(s, 1);
        s += __shfl_xor(s, 2);
        s += __shfl_xor(s, 4);
        s += __shfl_xor(s, 8);
        const float wp = e / s;

        float s0 = h2f(rb[h * 2 + 0]);
        float s1 = h2f(rb[h * 2 + 1]);
        s0 = fminf(fmaxf(1.f / (1.f + __expf(-s0)), 0.25f), 0.75f);
        s1 = fminf(fmaxf(1.f / (1.f + __expf(-s1)), 0.25f), 0.75f);

        const unsigned oo = *(const unsigned*)(const void*)(rb + 16 + (h * NPNT + p) * 2);
        const float o0 = 1.f / (1.f + __expf(-h2f((u16)(oo & 0xffffu))));
        const float o1 = 1.f / (1.f + __expf(-h2f((u16)(oo >> 16))));

        const int xl = l & (WW - 1);
        const int yl = l >> 6;
        const float cx = ((float)xl + 0.5f) / ((float)WW + 1e-6f);
        const float cy = ((float)yl + 0.5f) / ((float)HH + 1e-6f);

        float gx = fminf(fmaxf(cx - 0.5f * s0 + o0 * s0, 0.f), 1.f);
        float gy = fminf(fmaxf(cy - 0.5f * s1 + o1 * s1, 0.f), 1.f);
        const float ix = gx * (float)(WW - 1);
        const float iy = gy * (float)(HH - 1);
        const int x0 = min(max((int)floorf(ix), 0), WW - 2);
        const int y0 = min(max((int)floorf(iy), 0), HH - 2);
        const float wx = ix - (float)x0;
        const float wy = iy - (float)y0;

        srec[gi][p][0] = __int_as_float((y0 * WW + x0) * HD);
        srec[gi][p][1] = wx;
        srec[gi][p][2] = wy;
        srec[gi][p][3] = wp;
    }
    __syncthreads();

    const int gi = tid >> 3;
    const int j  = tid & 7;
    const int g  = blockIdx.x * 32 + gi;
    const int l  = g & (LL - 1);
    const int h  = (g >> 12) & (NHEAD - 1);
    const int b  = g >> 15;
    const u16* mb = mem2 + (size_t)(b * NHEAD + h) * LL * HD + j * 8;
    const bool hiSide = (j >= 4);

    float acc[8] = {};
    #pragma unroll
    for (int p = 0; p < NPNT; ++p) {
        const float4 rec = *(const float4*)&srec[gi][p][0];
        const int off   = __float_as_int(rec.x);
        const float fx  = hiSide ? rec.y : (1.f - rec.y);
        const float wf  = rec.w * fx;
        const h2 wp2 = __builtin_bit_cast(h2,
            __builtin_amdgcn_cvt_pkrtz(wf * (1.f - rec.z), wf * rec.z));
        const u16* p0 = mb + off;
        const uint4 V0 = *(const uint4*)(const void*)p0;               // row y0
        const uint4 V1 = *(const uint4*)(const void*)(p0 + WW * HD);   // row y0+1
        const unsigned v0w[4] = {V0.x, V0.y, V0.z, V0.w};
        const unsigned v1w[4] = {V1.x, V1.y, V1.z, V1.w};
        #pragma unroll
        for (int wd = 0; wd < 4; ++wd) {
            const unsigned plo = __builtin_amdgcn_perm(v1w[wd], v0w[wd], 0x05040100u);
            const unsigned phi = __builtin_amdgcn_perm(v1w[wd], v0w[wd], 0x07060302u);
            acc[2*wd]   = __builtin_amdgcn_fdot2(__builtin_bit_cast(h2, plo), wp2, acc[2*wd],   false);
            acc[2*wd+1] = __builtin_amdgcn_fdot2(__builtin_bit_cast(h2, phi), wp2, acc[2*wd+1], false);
        }
    }

    #pragma unroll
    for (int e = 0; e < 8; ++e)
        acc[e] += __shfl_xor(acc[e], 4);   // combine x0-side + x1-side

    if (j < 4) {
        ushort4 ha, hb;
        ha.x = f2h(acc[0]); ha.y = f2h(acc[1]); ha.z = f2h(acc[2]); ha.w = f2h(acc[3]);
        hb.x = f2h(acc[4]); hb.y = f2h(acc[5]); hb.z = f2h(acc[6]); hb.w = f2h(acc[7]);
        u16* dst = preH + ((size_t)(b * LL + l)) * KK + h * HD + j * 8;
        *(ushort4*)dst       = ha;
        *(ushort4*)(dst + 4) = hb;
    }
}

extern "C" void kernel_launch(void* const* d_in, const int* in_sizes, int n_in,
                              void* d_out, int out_size, void* d_ws, size_t ws_size,
                              hipStream_t stream) {
    const float* feat  = (const float*)d_in[0];
    const float* vw    = (const float*)d_in[1];
    const float* vb    = (const float*)d_in[2];
    const float* sw    = (const float*)d_in[3];
    const float* sb    = (const float*)d_in[4];
    const float* adw   = (const float*)d_in[5];
    const float* adb   = (const float*)d_in[6];
    const float* atw   = (const float*)d_in[7];
    const float* atb   = (const float*)d_in[8];
    const float* pw    = (const float*)d_in[9];
    const float* gamma = (const float*)d_in[10];
    const float* beta  = (const float*)d_in[11];
    float* out = (float*)d_out;
    char* ws = (char*)d_ws;

    // workspace layout (bytes)
    u16* mem2   = (u16*)(ws + 0);          // 4 MB (f16)
    u16* rawp   = (u16*)(ws + 4194304);    // 6.55 MB (f16, B*L*400)
    u16* preH   = (u16*)(ws + 10747904);   // 4 MB (f16)
    u16* wch    = (u16*)(ws + 14942208);   // 384 KB (768 rows, f16)
    float* bcat = (float*)(ws + 15335424); // 3 KB
    u16* pwh    = (u16*)(ws + 15339520);   // 128 KB (f16)

    // weights -> f16
    wprep_k<<<dim3(256), dim3(256), 0, stream>>>(vw, vb, adw, adb, atw, atb,
                                                 sw, sb, pw, wch, bcat, pwh);
    // fused feat-stage + all projections (BM=64, 8 waves, 384 blocks)
    projf_k<<<dim3(384), dim3(512), 0, stream>>>(feat, wch, bcat, mem2, rawp);
    // sampling -> preH f16 (f16 dot2 gathers, f16 rawp)
    sample5_k<<<dim3(2048), dim3(256), 0, stream>>>(mem2, rawp, preH);
    // out projection + BN (f16 MFMA)
    mgemm1_k<<<dim3(4, 128), dim3(64), 0, stream>>>(pwh, preH, gamma, beta, out);
}